// Round 16
// baseline (9239.234 us; speedup 1.0000x reference)
//
#include <hip/hip_runtime.h>
#include <math.h>

// LSTM forward: T=1024, B=64, I=256, H=512 (4H=2048), fp32 in/out.
// Round 16: DATA-AS-FLAG h exchange. R14/R15 showed the step time is a
//   serial chain of ~4 coherent fabric round trips (h-store drain, flag
//   visibility, poll, h-load). Here h travels as (value, epoch) uint2 in a
//   double-buffered IF$-resident exchange array: producer = one 8B coherent
//   store (single-copy atomic); consumer polls its own 16 pairs directly.
//   Drain, flag store, and separate data load all disappear: 2 trips.
//   d_out becomes a plain fire-and-forget store (nothing reads it anymore).
//   Barriers/step: 2 (was 4). Double-buffer + dependency chain make epoch
//   overwrite-before-read impossible within a row group.
// block = (rg: 16 rows) x (cg: 8 cells); 4 x 64 = 256 blocks x 512 thr.
// bf16-split MFMA (AhBh+AhBl+AlBh, R13-verified), W-frags in regs,
// linear conflict-free fragment staging (R14-verified).

#define TT      1024
#define BB      64
#define II      256
#define HH      512
#define G4H     2048
#define RPB     16
#define NRG     4
#define NCG     64
#define THREADS 512

typedef short  bf16x8 __attribute__((ext_vector_type(8)));
typedef float  f32x4  __attribute__((ext_vector_type(4)));

__device__ __forceinline__ unsigned int cvtpk_bf16(float a, float b) {
    unsigned int r;
    asm volatile("v_cvt_pk_bf16_f32 %0, %1, %2" : "=v"(r) : "v"(a), "v"(b));
    return r;   // lo16 = bf16(a), hi16 = bf16(b), RNE
}
__device__ __forceinline__ void coh_store_u2(uint2* p, uint2 v) {
    asm volatile("global_store_dwordx2 %0, %1, off sc0 sc1"
                 :: "v"(p), "v"(v) : "memory");
}
__device__ __forceinline__ float fast_tanh(float v) {
    const float e = __expf(-2.0f * fabsf(v));
    const float r = (1.0f - e) / (1.0f + e);
    return v < 0.0f ? -r : r;
}
__device__ __forceinline__ float sigm(float v) {
    return 1.0f / (1.0f + __expf(-v));
}

// convert 8 consecutive k-elements of one fragment into hi/lo bf16x8
__device__ __forceinline__ void cvt_frag(float4 v0, float4 v1,
                                         uint4& hi, uint4& lo) {
    hi.x = cvtpk_bf16(v0.x, v0.y);
    hi.y = cvtpk_bf16(v0.z, v0.w);
    hi.z = cvtpk_bf16(v1.x, v1.y);
    hi.w = cvtpk_bf16(v1.z, v1.w);
    lo.x = cvtpk_bf16(v0.x - __uint_as_float(hi.x << 16),
                      v0.y - __uint_as_float(hi.x & 0xffff0000u));
    lo.y = cvtpk_bf16(v0.z - __uint_as_float(hi.y << 16),
                      v0.w - __uint_as_float(hi.y & 0xffff0000u));
    lo.z = cvtpk_bf16(v1.x - __uint_as_float(hi.z << 16),
                      v1.y - __uint_as_float(hi.z & 0xffff0000u));
    lo.w = cvtpk_bf16(v1.z - __uint_as_float(hi.w << 16),
                      v1.w - __uint_as_float(hi.w & 0xffff0000u));
}

__global__ void init_hx(uint4* p) {          // zero 512KB (epochs must be 0)
    p[blockIdx.x * 256 + threadIdx.x] = (uint4){0u, 0u, 0u, 0u};
}

__global__ __launch_bounds__(THREADS) void lstm_persist(
    const float* __restrict__ x,    // [T][B][I]
    const float* __restrict__ Wi,   // [I][4H]
    const float* __restrict__ Wh,   // [H][4H]
    const float* __restrict__ bi,   // [4H]
    const float* __restrict__ bh,   // [4H]
    const float* __restrict__ h0p,  // [B][H]
    const float* __restrict__ c0p,  // [B][H]
    float* __restrict__ out,        // [T][B][H]
    uint2* __restrict__ hx)         // [2][64][512] (value, epoch), zeroed
{
    const int tid   = threadIdx.x;
    const int cg    = blockIdx.x & 63;
    const int rg    = blockIdx.x >> 6;
    const int row0  = rg * RPB;
    const int cell0 = cg * 8;
    const int wv    = tid >> 6;
    const int lane  = tid & 63;
    const int n2    = wv >> 2;            // N-tile (cols 16*n2..)
    const int k4    = wv & 3;             // K-chunk

    __shared__ uint4 aFH[24 * 64];        // A hi frags (kk 0..23)
    __shared__ uint4 aFL[24 * 64];        // A lo
    __shared__ float red[8 * 64 * 4];     // per-wave C partials
    __shared__ float c_lds[RPB][8];

    const int s_ls = tid & 63;
    const int s_r  = s_ls & 15;
    const int s_kb = (tid >> 6) * 32 + ((s_ls >> 4) & 3) * 8;

    // ---- one-time: W fragments -> registers (6 kk slots x hi/lo) ----
    bf16x8 wH[6], wL[6];
    {
        const int col = n2 * 16 + (lane & 15);
        const int J   = (col >> 3) * HH + cell0 + (col & 7);
        #pragma unroll
        for (int s = 0; s < 6; ++s) {
            const int kk = (s < 2) ? (k4 * 2 + s) : (8 + k4 * 4 + (s - 2));
            const int kb = kk * 32 + (lane >> 4) * 8;
            float w[8];
            #pragma unroll
            for (int e = 0; e < 8; ++e) {
                const int k = kb + e;
                w[e] = (k < II) ? Wi[(size_t)k * G4H + J]
                                : Wh[(size_t)(k - II) * G4H + J];
            }
            uint4 hi, lo;
            cvt_frag(make_float4(w[0], w[1], w[2], w[3]),
                     make_float4(w[4], w[5], w[6], w[7]), hi, lo);
            wH[s] = *(bf16x8*)&hi;
            wL[s] = *(bf16x8*)&lo;
        }
    }

    // ---- update-role constants (threads 0..127) ----
    float b4[4];
    if (tid < 128) {
        const int r = tid >> 3, m8 = tid & 7;
        #pragma unroll
        for (int g = 0; g < 4; ++g)
            b4[g] = bi[g * HH + cell0 + m8] + bh[g * HH + cell0 + m8];
        c_lds[r][m8] = c0p[(size_t)(row0 + r) * HH + cell0 + m8];
    }

    // ---- prologue: stage x_0 and h0 fragments (linear writes) ----
    {
        const float* xr = x + (size_t)(row0 + s_r) * II + s_kb;
        uint4 hi, lo;
        cvt_frag(*(const float4*)xr, *(const float4*)(xr + 4), hi, lo);
        aFH[tid] = hi; aFL[tid] = lo;

        const float* hr = h0p + (size_t)(row0 + s_r) * HH + s_kb;
        cvt_frag(*(const float4*)hr, *(const float4*)(hr + 4), hi, lo);
        aFH[512 + tid] = hi; aFL[512 + tid] = lo;
        cvt_frag(*(const float4*)(hr + 256), *(const float4*)(hr + 260), hi, lo);
        aFH[1024 + tid] = hi; aFL[1024 + tid] = lo;
    }
    __syncthreads();

    // ---- x-MFMA for t=0 ----
    f32x4 acc = {0.f, 0.f, 0.f, 0.f};
    #pragma unroll
    for (int q = 0; q < 2; ++q) {
        const int kk = k4 * 2 + q;
        const bf16x8 ah = *(const bf16x8*)&aFH[kk * 64 + lane];
        const bf16x8 al = *(const bf16x8*)&aFL[kk * 64 + lane];
        acc = __builtin_amdgcn_mfma_f32_16x16x32_bf16(ah, wH[q], acc, 0, 0, 0);
        acc = __builtin_amdgcn_mfma_f32_16x16x32_bf16(ah, wL[q], acc, 0, 0, 0);
        acc = __builtin_amdgcn_mfma_f32_16x16x32_bf16(al, wH[q], acc, 0, 0, 0);
    }

    for (int t = 0; t < TT; ++t) {
        const bool more = (t + 1 < TT);

        // ---- issue x_{t+1} loads early ----
        float4 xv0, xv1;
        if (more) {
            const float* xr = x + ((size_t)(t + 1) * BB + row0 + s_r) * II + s_kb;
            xv0 = *(const float4*)xr;
            xv1 = *(const float4*)(xr + 4);
        }

        // ---- h-MFMA, acc carries x part ----
        #pragma unroll
        for (int q = 0; q < 4; ++q) {
            const int kk = 8 + k4 * 4 + q;
            const bf16x8 ah = *(const bf16x8*)&aFH[kk * 64 + lane];
            const bf16x8 al = *(const bf16x8*)&aFL[kk * 64 + lane];
            acc = __builtin_amdgcn_mfma_f32_16x16x32_bf16(ah, wH[2 + q], acc, 0, 0, 0);
            acc = __builtin_amdgcn_mfma_f32_16x16x32_bf16(ah, wL[2 + q], acc, 0, 0, 0);
            acc = __builtin_amdgcn_mfma_f32_16x16x32_bf16(al, wH[2 + q], acc, 0, 0, 0);
        }

        // ---- publish C partial; stage x_{t+1} ----
        ((f32x4*)red)[wv * 64 + lane] = acc;
        if (more) {
            uint4 hi, lo;
            cvt_frag(xv0, xv1, hi, lo);
            aFH[tid] = hi; aFL[tid] = lo;
        }
        __syncthreads();                        // S1

        // ---- cell update (threads 0..127): h -> out (plain) + hx (tagged) ----
        if (tid < 128) {
            const int r = tid >> 3, m8 = tid & 7;
            const int lane_c_base = 16 * (r >> 2);
            const int reg = r & 3;
            float g4[4];
            #pragma unroll
            for (int g = 0; g < 4; ++g) {
                const int col = g * 8 + m8;
                const int nn  = col >> 4, cl = col & 15;
                const int lc  = cl + lane_c_base;
                float s = b4[g];
                #pragma unroll
                for (int p = 0; p < 4; ++p)
                    s += red[((nn * 4 + p) * 64 + lc) * 4 + reg];
                g4[g] = s;
            }
            const float ig = sigm(g4[0]);
            const float fg = sigm(g4[1]);
            const float gg = fast_tanh(g4[2]);
            const float og = sigm(g4[3]);
            const float cn = fg * c_lds[r][m8] + ig * gg;
            c_lds[r][m8] = cn;
            const float hv = og * fast_tanh(cn);
            out[((size_t)t * BB + row0 + r) * HH + cell0 + m8] = hv;  // plain
            if (more) {
                uint2 pr; pr.x = __float_as_uint(hv);
                pr.y = (unsigned int)(t + 1);
                coh_store_u2(&hx[((size_t)(t & 1) * BB + row0 + r) * HH
                                 + cell0 + m8], pr);
            }
        }

        if (more) {
            // ---- window: x-MFMA for t+1 (absorbs peer skew) ----
            acc = (f32x4){0.f, 0.f, 0.f, 0.f};
            #pragma unroll
            for (int q = 0; q < 2; ++q) {
                const int kk = k4 * 2 + q;
                const bf16x8 ah = *(const bf16x8*)&aFH[kk * 64 + lane];
                const bf16x8 al = *(const bf16x8*)&aFL[kk * 64 + lane];
                acc = __builtin_amdgcn_mfma_f32_16x16x32_bf16(ah, wH[q], acc, 0, 0, 0);
                acc = __builtin_amdgcn_mfma_f32_16x16x32_bf16(ah, wL[q], acc, 0, 0, 0);
                acc = __builtin_amdgcn_mfma_f32_16x16x32_bf16(al, wH[q], acc, 0, 0, 0);
            }

            // ---- poll-load h_t: 16 (value, epoch) pairs per thread ----
            const uint2* hb = hx + ((size_t)(t & 1) * BB + row0 + s_r) * HH + s_kb;
            uint4 q0, q1, q2, q3, q4, q5, q6, q7;
            const unsigned int tgt = (unsigned int)(t + 1);
            for (;;) {
                asm volatile(
                    "global_load_dwordx4 %0, %8, off sc0 sc1\n\t"
                    "global_load_dwordx4 %1, %8, off offset:16 sc0 sc1\n\t"
                    "global_load_dwordx4 %2, %8, off offset:32 sc0 sc1\n\t"
                    "global_load_dwordx4 %3, %8, off offset:48 sc0 sc1\n\t"
                    "global_load_dwordx4 %4, %8, off offset:2048 sc0 sc1\n\t"
                    "global_load_dwordx4 %5, %8, off offset:2064 sc0 sc1\n\t"
                    "global_load_dwordx4 %6, %8, off offset:2080 sc0 sc1\n\t"
                    "global_load_dwordx4 %7, %8, off offset:2096 sc0 sc1\n\t"
                    "s_waitcnt vmcnt(0)"
                    : "=&v"(q0), "=&v"(q1), "=&v"(q2), "=&v"(q3),
                      "=&v"(q4), "=&v"(q5), "=&v"(q6), "=&v"(q7)
                    : "v"(hb)
                    : "memory");
                const bool ok =
                    (q0.y == tgt) & (q0.w == tgt) & (q1.y == tgt) & (q1.w == tgt) &
                    (q2.y == tgt) & (q2.w == tgt) & (q3.y == tgt) & (q3.w == tgt) &
                    (q4.y == tgt) & (q4.w == tgt) & (q5.y == tgt) & (q5.w == tgt) &
                    (q6.y == tgt) & (q6.w == tgt) & (q7.y == tgt) & (q7.w == tgt);
                if (ok) break;
                __builtin_amdgcn_s_sleep(1);
            }

            // ---- stage h_t fragments (linear writes) ----
            {
                uint4 hi, lo;
                const float4 a0 = make_float4(__uint_as_float(q0.x),
                                              __uint_as_float(q0.z),
                                              __uint_as_float(q1.x),
                                              __uint_as_float(q1.z));
                const float4 a1 = make_float4(__uint_as_float(q2.x),
                                              __uint_as_float(q2.z),
                                              __uint_as_float(q3.x),
                                              __uint_as_float(q3.z));
                cvt_frag(a0, a1, hi, lo);
                aFH[512 + tid] = hi; aFL[512 + tid] = lo;
                const float4 b0 = make_float4(__uint_as_float(q4.x),
                                              __uint_as_float(q4.z),
                                              __uint_as_float(q5.x),
                                              __uint_as_float(q5.z));
                const float4 b1 = make_float4(__uint_as_float(q6.x),
                                              __uint_as_float(q6.z),
                                              __uint_as_float(q7.x),
                                              __uint_as_float(q7.z));
                cvt_frag(b0, b1, hi, lo);
                aFH[1024 + tid] = hi; aFL[1024 + tid] = lo;
            }
            __syncthreads();                    // S2 (final)
        }
    }
}

extern "C" void kernel_launch(void* const* d_in, const int* in_sizes, int n_in,
                              void* d_out, int out_size, void* d_ws, size_t ws_size,
                              hipStream_t stream) {
    const float* x  = (const float*)d_in[0];
    const float* Wi = (const float*)d_in[1];
    const float* Wh = (const float*)d_in[2];
    const float* bi = (const float*)d_in[3];
    const float* bh = (const float*)d_in[4];
    const float* h0 = (const float*)d_in[5];
    const float* c0 = (const float*)d_in[6];
    float* out = (float*)d_out;
    uint2* hx = (uint2*)d_ws;                   // 2*64*512 uint2 = 512 KB

    init_hx<<<128, 256, 0, stream>>>((uint4*)d_ws);  // zero epochs

    void* args[] = { (void*)&x, (void*)&Wi, (void*)&Wh, (void*)&bi,
                     (void*)&bh, (void*)&h0, (void*)&c0, (void*)&out,
                     (void*)&hx };
    hipError_t e = hipLaunchCooperativeKernel((const void*)lstm_persist,
                                              dim3(NRG * NCG), dim3(THREADS),
                                              args, 0, stream);
    if (e != hipSuccess) {
        (void)hipGetLastError();
        lstm_persist<<<dim3(NRG * NCG), dim3(THREADS), 0, stream>>>(
            x, Wi, Wh, bi, bh, h0, c0, out, hx);
    }
}

// Round 17
// 5138.866 us; speedup vs baseline: 1.7979x; 1.7979x over previous
//
#include <hip/hip_runtime.h>
#include <math.h>

// LSTM forward: T=1024, B=64, I=256, H=512 (4H=2048), fp32 in/out.
// Round 17: counter-paced, epoch-validated h exchange.
//   R14 chain: drain(trip) -> add(trip) -> tid0 poll(trip) -> gather(trip).
//   R16 lesson: epochs-on-data works, but 8192-thread poll LOOPS congest
//   the fabric (single-reader rule). Here:
//   * producers store (h, epoch=t+1) as 8B sc0/sc1 single-copy-atomic pairs
//     into double-buffered hx[t&1]; NO vmcnt drain (epochs carry correctness)
//   * tid0 atomicAdds the row-group counter right after the issue barrier;
//     its visibility+detection latency overlaps the h-stores' flight
//   * consumers: tid0-only spin (paced) -> barrier -> ONE mass gather with
//     epoch validation; retry loop is a rare safety net, not a poll
//   Double-buffer overwrite safety: P at step t+2 gathered epoch t+2 ->
//   all peers finished step t+1 -> all peers consumed epoch t+1. QED.
// block = (rg: 16 rows) x (cg: 8 cells); 4 x 64 = 256 blocks x 512 thr.
// bf16-split MFMA (R13-verified), W-frags in regs, linear staging (R14).

#define TT      1024
#define BB      64
#define II      256
#define HH      512
#define G4H     2048
#define RPB     16
#define NRG     4
#define NCG     64
#define THREADS 512

typedef short  bf16x8 __attribute__((ext_vector_type(8)));
typedef float  f32x4  __attribute__((ext_vector_type(4)));

__device__ __forceinline__ unsigned int cvtpk_bf16(float a, float b) {
    unsigned int r;
    asm volatile("v_cvt_pk_bf16_f32 %0, %1, %2" : "=v"(r) : "v"(a), "v"(b));
    return r;   // lo16 = bf16(a), hi16 = bf16(b), RNE
}
__device__ __forceinline__ void coh_store_u2(uint2* p, uint2 v) {
    asm volatile("global_store_dwordx2 %0, %1, off sc0 sc1"
                 :: "v"(p), "v"(v) : "memory");
}
__device__ __forceinline__ float fast_tanh(float v) {
    const float e = __expf(-2.0f * fabsf(v));
    const float r = (1.0f - e) / (1.0f + e);
    return v < 0.0f ? -r : r;
}
__device__ __forceinline__ float sigm(float v) {
    return 1.0f / (1.0f + __expf(-v));
}

// convert 8 consecutive k-elements of one fragment into hi/lo bf16x8
__device__ __forceinline__ void cvt_frag(float4 v0, float4 v1,
                                         uint4& hi, uint4& lo) {
    hi.x = cvtpk_bf16(v0.x, v0.y);
    hi.y = cvtpk_bf16(v0.z, v0.w);
    hi.z = cvtpk_bf16(v1.x, v1.y);
    hi.w = cvtpk_bf16(v1.z, v1.w);
    lo.x = cvtpk_bf16(v0.x - __uint_as_float(hi.x << 16),
                      v0.y - __uint_as_float(hi.x & 0xffff0000u));
    lo.y = cvtpk_bf16(v0.z - __uint_as_float(hi.y << 16),
                      v0.w - __uint_as_float(hi.y & 0xffff0000u));
    lo.z = cvtpk_bf16(v1.x - __uint_as_float(hi.z << 16),
                      v1.y - __uint_as_float(hi.z & 0xffff0000u));
    lo.w = cvtpk_bf16(v1.z - __uint_as_float(hi.w << 16),
                      v1.w - __uint_as_float(hi.w & 0xffff0000u));
}

__global__ void init_hx(uint4* p) {          // zero 512KB (epochs must be 0)
    p[blockIdx.x * 256 + threadIdx.x] = (uint4){0u, 0u, 0u, 0u};
}
__global__ void init_ctr(unsigned int* c) { c[threadIdx.x] = 0; }

__global__ __launch_bounds__(THREADS) void lstm_persist(
    const float* __restrict__ x,    // [T][B][I]
    const float* __restrict__ Wi,   // [I][4H]
    const float* __restrict__ Wh,   // [H][4H]
    const float* __restrict__ bi,   // [4H]
    const float* __restrict__ bh,   // [4H]
    const float* __restrict__ h0p,  // [B][H]
    const float* __restrict__ c0p,  // [B][H]
    float* __restrict__ out,        // [T][B][H]
    uint2* __restrict__ hx,         // [2][64][512] (value, epoch), zeroed
    unsigned int* __restrict__ ctr) // [NRG*32], zeroed
{
    const int tid   = threadIdx.x;
    const int cg    = blockIdx.x & 63;
    const int rg    = blockIdx.x >> 6;
    const int row0  = rg * RPB;
    const int cell0 = cg * 8;
    const int wv    = tid >> 6;
    const int lane  = tid & 63;
    const int n2    = wv >> 2;            // N-tile (cols 16*n2..)
    const int k4    = wv & 3;             // K-chunk

    __shared__ uint4 aFH[24 * 64];        // A hi frags (kk 0..23)
    __shared__ uint4 aFL[24 * 64];        // A lo
    __shared__ float red[8 * 64 * 4];     // per-wave C partials
    __shared__ float c_lds[RPB][8];

    const int s_ls = tid & 63;
    const int s_r  = s_ls & 15;
    const int s_kb = (tid >> 6) * 32 + ((s_ls >> 4) & 3) * 8;

    // ---- one-time: W fragments -> registers (6 kk slots x hi/lo) ----
    bf16x8 wH[6], wL[6];
    {
        const int col = n2 * 16 + (lane & 15);
        const int J   = (col >> 3) * HH + cell0 + (col & 7);
        #pragma unroll
        for (int s = 0; s < 6; ++s) {
            const int kk = (s < 2) ? (k4 * 2 + s) : (8 + k4 * 4 + (s - 2));
            const int kb = kk * 32 + (lane >> 4) * 8;
            float w[8];
            #pragma unroll
            for (int e = 0; e < 8; ++e) {
                const int k = kb + e;
                w[e] = (k < II) ? Wi[(size_t)k * G4H + J]
                                : Wh[(size_t)(k - II) * G4H + J];
            }
            uint4 hi, lo;
            cvt_frag(make_float4(w[0], w[1], w[2], w[3]),
                     make_float4(w[4], w[5], w[6], w[7]), hi, lo);
            wH[s] = *(bf16x8*)&hi;
            wL[s] = *(bf16x8*)&lo;
        }
    }

    // ---- update-role constants (threads 0..127) ----
    float b4[4];
    if (tid < 128) {
        const int r = tid >> 3, m8 = tid & 7;
        #pragma unroll
        for (int g = 0; g < 4; ++g)
            b4[g] = bi[g * HH + cell0 + m8] + bh[g * HH + cell0 + m8];
        c_lds[r][m8] = c0p[(size_t)(row0 + r) * HH + cell0 + m8];
    }

    // ---- prologue: stage x_0 and h0 fragments (linear writes) ----
    {
        const float* xr = x + (size_t)(row0 + s_r) * II + s_kb;
        uint4 hi, lo;
        cvt_frag(*(const float4*)xr, *(const float4*)(xr + 4), hi, lo);
        aFH[tid] = hi; aFL[tid] = lo;

        const float* hr = h0p + (size_t)(row0 + s_r) * HH + s_kb;
        cvt_frag(*(const float4*)hr, *(const float4*)(hr + 4), hi, lo);
        aFH[512 + tid] = hi; aFL[512 + tid] = lo;
        cvt_frag(*(const float4*)(hr + 256), *(const float4*)(hr + 260), hi, lo);
        aFH[1024 + tid] = hi; aFL[1024 + tid] = lo;
    }
    __syncthreads();

    // ---- x-MFMA for t=0 ----
    f32x4 acc = {0.f, 0.f, 0.f, 0.f};
    #pragma unroll
    for (int q = 0; q < 2; ++q) {
        const int kk = k4 * 2 + q;
        const bf16x8 ah = *(const bf16x8*)&aFH[kk * 64 + lane];
        const bf16x8 al = *(const bf16x8*)&aFL[kk * 64 + lane];
        acc = __builtin_amdgcn_mfma_f32_16x16x32_bf16(ah, wH[q], acc, 0, 0, 0);
        acc = __builtin_amdgcn_mfma_f32_16x16x32_bf16(ah, wL[q], acc, 0, 0, 0);
        acc = __builtin_amdgcn_mfma_f32_16x16x32_bf16(al, wH[q], acc, 0, 0, 0);
    }

    unsigned int* myctr = ctr + rg * 32;

    for (int t = 0; t < TT; ++t) {
        const bool more = (t + 1 < TT);

        // ---- issue x_{t+1} loads early ----
        float4 xv0, xv1;
        if (more) {
            const float* xr = x + ((size_t)(t + 1) * BB + row0 + s_r) * II + s_kb;
            xv0 = *(const float4*)xr;
            xv1 = *(const float4*)(xr + 4);
        }

        // ---- h-MFMA, acc carries x part ----
        #pragma unroll
        for (int q = 0; q < 4; ++q) {
            const int kk = 8 + k4 * 4 + q;
            const bf16x8 ah = *(const bf16x8*)&aFH[kk * 64 + lane];
            const bf16x8 al = *(const bf16x8*)&aFL[kk * 64 + lane];
            acc = __builtin_amdgcn_mfma_f32_16x16x32_bf16(ah, wH[2 + q], acc, 0, 0, 0);
            acc = __builtin_amdgcn_mfma_f32_16x16x32_bf16(ah, wL[2 + q], acc, 0, 0, 0);
            acc = __builtin_amdgcn_mfma_f32_16x16x32_bf16(al, wH[2 + q], acc, 0, 0, 0);
        }

        // ---- publish C partial; stage x_{t+1} ----
        ((f32x4*)red)[wv * 64 + lane] = acc;
        if (more) {
            uint4 hi, lo;
            cvt_frag(xv0, xv1, hi, lo);
            aFH[tid] = hi; aFL[tid] = lo;
        }
        __syncthreads();                        // S1

        // ---- cell update (threads 0..127): out (plain) + hx (tagged) ----
        if (tid < 128) {
            const int r = tid >> 3, m8 = tid & 7;
            const int lane_c_base = 16 * (r >> 2);
            const int reg = r & 3;
            float g4[4];
            #pragma unroll
            for (int g = 0; g < 4; ++g) {
                const int col = g * 8 + m8;
                const int nn  = col >> 4, cl = col & 15;
                const int lc  = cl + lane_c_base;
                float s = b4[g];
                #pragma unroll
                for (int p = 0; p < 4; ++p)
                    s += red[((nn * 4 + p) * 64 + lc) * 4 + reg];
                g4[g] = s;
            }
            const float ig = sigm(g4[0]);
            const float fg = sigm(g4[1]);
            const float gg = fast_tanh(g4[2]);
            const float og = sigm(g4[3]);
            const float cn = fg * c_lds[r][m8] + ig * gg;
            c_lds[r][m8] = cn;
            const float hv = og * fast_tanh(cn);
            out[((size_t)t * BB + row0 + r) * HH + cell0 + m8] = hv;  // plain
            if (more) {
                uint2 pr; pr.x = __float_as_uint(hv);
                pr.y = (unsigned int)(t + 1);
                coh_store_u2(&hx[((size_t)(t & 1) * BB + row0 + r) * HH
                                 + cell0 + m8], pr);
            }
        }

        __syncthreads();                        // S2 (issue order; NO drain)
        if (more) {
            // ---- arrive immediately; h-stores' flight overlaps detection ----
            if (tid == 0)
                __hip_atomic_fetch_add(myctr, 1u, __ATOMIC_RELAXED,
                                       __HIP_MEMORY_SCOPE_AGENT);

            // ---- window: x-MFMA for t+1 (absorbs skew) ----
            acc = (f32x4){0.f, 0.f, 0.f, 0.f};
            #pragma unroll
            for (int q = 0; q < 2; ++q) {
                const int kk = k4 * 2 + q;
                const bf16x8 ah = *(const bf16x8*)&aFH[kk * 64 + lane];
                const bf16x8 al = *(const bf16x8*)&aFL[kk * 64 + lane];
                acc = __builtin_amdgcn_mfma_f32_16x16x32_bf16(ah, wH[q], acc, 0, 0, 0);
                acc = __builtin_amdgcn_mfma_f32_16x16x32_bf16(ah, wL[q], acc, 0, 0, 0);
                acc = __builtin_amdgcn_mfma_f32_16x16x32_bf16(al, wH[q], acc, 0, 0, 0);
            }

            // ---- tid0-ONLY spin (single-reader rule) ----
            if (tid == 0) {
                const unsigned int target = 64u * (unsigned int)(t + 1);
                while (__hip_atomic_load(myctr, __ATOMIC_RELAXED,
                                         __HIP_MEMORY_SCOPE_AGENT) < target) {
                    __builtin_amdgcn_s_sleep(2);
                }
            }
            __syncthreads();                    // S3

            // ---- single-shot gather of tagged h; rare-retry validation ----
            const uint2* hb = hx + ((size_t)(t & 1) * BB + row0 + s_r) * HH + s_kb;
            uint4 q0, q1, q2, q3, q4, q5, q6, q7;
            const unsigned int tgt = (unsigned int)(t + 1);
            for (;;) {
                asm volatile(
                    "global_load_dwordx4 %0, %8, off sc0 sc1\n\t"
                    "global_load_dwordx4 %1, %8, off offset:16 sc0 sc1\n\t"
                    "global_load_dwordx4 %2, %8, off offset:32 sc0 sc1\n\t"
                    "global_load_dwordx4 %3, %8, off offset:48 sc0 sc1\n\t"
                    "global_load_dwordx4 %4, %8, off offset:2048 sc0 sc1\n\t"
                    "global_load_dwordx4 %5, %8, off offset:2064 sc0 sc1\n\t"
                    "global_load_dwordx4 %6, %8, off offset:2080 sc0 sc1\n\t"
                    "global_load_dwordx4 %7, %8, off offset:2096 sc0 sc1\n\t"
                    "s_waitcnt vmcnt(0)"
                    : "=&v"(q0), "=&v"(q1), "=&v"(q2), "=&v"(q3),
                      "=&v"(q4), "=&v"(q5), "=&v"(q6), "=&v"(q7)
                    : "v"(hb)
                    : "memory");
                const bool ok =
                    (q0.y == tgt) & (q0.w == tgt) & (q1.y == tgt) & (q1.w == tgt) &
                    (q2.y == tgt) & (q2.w == tgt) & (q3.y == tgt) & (q3.w == tgt) &
                    (q4.y == tgt) & (q4.w == tgt) & (q5.y == tgt) & (q5.w == tgt) &
                    (q6.y == tgt) & (q6.w == tgt) & (q7.y == tgt) & (q7.w == tgt);
                if (ok) break;
                __builtin_amdgcn_s_sleep(2);    // rare: pacing was insufficient
            }

            // ---- stage h_t fragments (linear writes) ----
            {
                uint4 hi, lo;
                const float4 a0 = make_float4(__uint_as_float(q0.x),
                                              __uint_as_float(q0.z),
                                              __uint_as_float(q1.x),
                                              __uint_as_float(q1.z));
                const float4 a1 = make_float4(__uint_as_float(q2.x),
                                              __uint_as_float(q2.z),
                                              __uint_as_float(q3.x),
                                              __uint_as_float(q3.z));
                cvt_frag(a0, a1, hi, lo);
                aFH[512 + tid] = hi; aFL[512 + tid] = lo;
                const float4 b0 = make_float4(__uint_as_float(q4.x),
                                              __uint_as_float(q4.z),
                                              __uint_as_float(q5.x),
                                              __uint_as_float(q5.z));
                const float4 b1 = make_float4(__uint_as_float(q6.x),
                                              __uint_as_float(q6.z),
                                              __uint_as_float(q7.x),
                                              __uint_as_float(q7.z));
                cvt_frag(b0, b1, hi, lo);
                aFH[1024 + tid] = hi; aFL[1024 + tid] = lo;
            }
            __syncthreads();                    // S4
        }
    }
}

extern "C" void kernel_launch(void* const* d_in, const int* in_sizes, int n_in,
                              void* d_out, int out_size, void* d_ws, size_t ws_size,
                              hipStream_t stream) {
    const float* x  = (const float*)d_in[0];
    const float* Wi = (const float*)d_in[1];
    const float* Wh = (const float*)d_in[2];
    const float* bi = (const float*)d_in[3];
    const float* bh = (const float*)d_in[4];
    const float* h0 = (const float*)d_in[5];
    const float* c0 = (const float*)d_in[6];
    float* out = (float*)d_out;

    uint2* hx = (uint2*)d_ws;                          // 512 KB
    unsigned int* ctr = (unsigned int*)((char*)d_ws + 2 * BB * HH * 8);

    init_hx<<<128, 256, 0, stream>>>((uint4*)d_ws);    // zero epochs
    init_ctr<<<1, 128, 0, stream>>>(ctr);

    void* args[] = { (void*)&x, (void*)&Wi, (void*)&Wh, (void*)&bi,
                     (void*)&bh, (void*)&h0, (void*)&c0, (void*)&out,
                     (void*)&hx, (void*)&ctr };
    hipError_t e = hipLaunchCooperativeKernel((const void*)lstm_persist,
                                              dim3(NRG * NCG), dim3(THREADS),
                                              args, 0, stream);
    if (e != hipSuccess) {
        (void)hipGetLastError();
        lstm_persist<<<dim3(NRG * NCG), dim3(THREADS), 0, stream>>>(
            x, Wi, Wh, bi, bh, h0, c0, out, hx, ctr);
    }
}

// Round 18
// 4293.766 us; speedup vs baseline: 2.1518x; 1.1968x over previous
//
#include <hip/hip_runtime.h>
#include <math.h>

// LSTM forward: T=1024, B=64, I=256, H=512 (4H=2048), fp32 in/out.
// Round 18: R14 skeleton (counter + drain + tid0 spin + single-shot gather;
//   R17 proved epoch-pacing retries cost more than the drain) with:
//   * producer-side bf16 hi/lo split: h travels as ONE u32 (hi16|lo16) in
//     hpk[2][64][512] -> gather is 16B/thread (4x dwordx4), consumers build
//     MFMA fragments with pure bit-ops (split computed once, not 64x)
//   * drain-overlap: only producer waves 0-1 execute vmcnt(0); waves 2-7
//     run their x-window MFMA between S1 and S2 (overlapping the drain),
//     waves 0-1 run theirs during the tid0 spin
// block = (rg: 16 rows) x (cg: 8 cells); 4 x 64 = 256 blocks x 512 thr.
// bf16-split MFMA (R13-verified), W-frags in regs, linear staging (R14).

#define TT      1024
#define BB      64
#define II      256
#define HH      512
#define G4H     2048
#define RPB     16
#define NRG     4
#define NCG     64
#define THREADS 512

typedef short  bf16x8 __attribute__((ext_vector_type(8)));
typedef float  f32x4  __attribute__((ext_vector_type(4)));

__device__ __forceinline__ unsigned int cvtpk_bf16(float a, float b) {
    unsigned int r;
    asm volatile("v_cvt_pk_bf16_f32 %0, %1, %2" : "=v"(r) : "v"(a), "v"(b));
    return r;   // lo16 = bf16(a), hi16 = bf16(b), RNE
}
__device__ __forceinline__ void coh_store_u(unsigned int* p, unsigned int v) {
    asm volatile("global_store_dword %0, %1, off sc0 sc1"
                 :: "v"(p), "v"(v) : "memory");
}
__device__ __forceinline__ float fast_tanh(float v) {
    const float e = __expf(-2.0f * fabsf(v));
    const float r = (1.0f - e) / (1.0f + e);
    return v < 0.0f ? -r : r;
}
__device__ __forceinline__ float sigm(float v) {
    return 1.0f / (1.0f + __expf(-v));
}

// convert 8 consecutive k-elements of one fragment into hi/lo bf16x8
__device__ __forceinline__ void cvt_frag(float4 v0, float4 v1,
                                         uint4& hi, uint4& lo) {
    hi.x = cvtpk_bf16(v0.x, v0.y);
    hi.y = cvtpk_bf16(v0.z, v0.w);
    hi.z = cvtpk_bf16(v1.x, v1.y);
    hi.w = cvtpk_bf16(v1.z, v1.w);
    lo.x = cvtpk_bf16(v0.x - __uint_as_float(hi.x << 16),
                      v0.y - __uint_as_float(hi.x & 0xffff0000u));
    lo.y = cvtpk_bf16(v0.z - __uint_as_float(hi.y << 16),
                      v0.w - __uint_as_float(hi.y & 0xffff0000u));
    lo.z = cvtpk_bf16(v1.x - __uint_as_float(hi.z << 16),
                      v1.y - __uint_as_float(hi.z & 0xffff0000u));
    lo.w = cvtpk_bf16(v1.z - __uint_as_float(hi.w << 16),
                      v1.w - __uint_as_float(hi.w & 0xffff0000u));
}

// unpack 8 packed u32 (hi16|lo16) -> fragment hi/lo words
// frag word u = (elem 2u in lo16, elem 2u+1 in hi16)
__device__ __forceinline__ void unpack8(uint4 a, uint4 b,
                                        uint4& fh, uint4& fl) {
    fh.x = (a.x >> 16) | (a.y & 0xffff0000u);
    fh.y = (a.z >> 16) | (a.w & 0xffff0000u);
    fh.z = (b.x >> 16) | (b.y & 0xffff0000u);
    fh.w = (b.z >> 16) | (b.w & 0xffff0000u);
    fl.x = (a.x & 0xffffu) | (a.y << 16);
    fl.y = (a.z & 0xffffu) | (a.w << 16);
    fl.z = (b.x & 0xffffu) | (b.w == 0 && false ? 0u : (b.w << 16));  // placeholder avoided below
    fl.z = (b.x & 0xffffu) | (b.y << 16);
    fl.w = (b.z & 0xffffu) | (b.w << 16);
}

__global__ void init_ctr(unsigned int* c) { c[threadIdx.x] = 0; }

__global__ __launch_bounds__(THREADS) void lstm_persist(
    const float* __restrict__ x,    // [T][B][I]
    const float* __restrict__ Wi,   // [I][4H]
    const float* __restrict__ Wh,   // [H][4H]
    const float* __restrict__ bi,   // [4H]
    const float* __restrict__ bh,   // [4H]
    const float* __restrict__ h0p,  // [B][H]
    const float* __restrict__ c0p,  // [B][H]
    float* __restrict__ out,        // [T][B][H]
    unsigned int* __restrict__ hpk, // [2][64][512] packed (hi16|lo16)
    unsigned int* __restrict__ ctr) // [NRG*32], zeroed
{
    const int tid   = threadIdx.x;
    const int cg    = blockIdx.x & 63;
    const int rg    = blockIdx.x >> 6;
    const int row0  = rg * RPB;
    const int cell0 = cg * 8;
    const int wv    = tid >> 6;
    const int lane  = tid & 63;
    const int n2    = wv >> 2;            // N-tile (cols 16*n2..)
    const int k4    = wv & 3;             // K-chunk

    __shared__ uint4 aFH[24 * 64];        // A hi frags (kk 0..23)
    __shared__ uint4 aFL[24 * 64];        // A lo
    __shared__ float red[8 * 64 * 4];     // per-wave C partials
    __shared__ float c_lds[RPB][8];

    const int s_ls = tid & 63;
    const int s_r  = s_ls & 15;
    const int s_kb = (tid >> 6) * 32 + ((s_ls >> 4) & 3) * 8;

    // ---- one-time: W fragments -> registers (6 kk slots x hi/lo) ----
    bf16x8 wH[6], wL[6];
    {
        const int col = n2 * 16 + (lane & 15);
        const int J   = (col >> 3) * HH + cell0 + (col & 7);
        #pragma unroll
        for (int s = 0; s < 6; ++s) {
            const int kk = (s < 2) ? (k4 * 2 + s) : (8 + k4 * 4 + (s - 2));
            const int kb = kk * 32 + (lane >> 4) * 8;
            float w[8];
            #pragma unroll
            for (int e = 0; e < 8; ++e) {
                const int k = kb + e;
                w[e] = (k < II) ? Wi[(size_t)k * G4H + J]
                                : Wh[(size_t)(k - II) * G4H + J];
            }
            uint4 hi, lo;
            cvt_frag(make_float4(w[0], w[1], w[2], w[3]),
                     make_float4(w[4], w[5], w[6], w[7]), hi, lo);
            wH[s] = *(bf16x8*)&hi;
            wL[s] = *(bf16x8*)&lo;
        }
    }

    // ---- update-role constants (threads 0..127) ----
    float b4[4];
    if (tid < 128) {
        const int r = tid >> 3, m8 = tid & 7;
        #pragma unroll
        for (int g = 0; g < 4; ++g)
            b4[g] = bi[g * HH + cell0 + m8] + bh[g * HH + cell0 + m8];
        c_lds[r][m8] = c0p[(size_t)(row0 + r) * HH + cell0 + m8];
    }

    // ---- prologue: stage x_0 and h0 fragments (linear writes) ----
    {
        const float* xr = x + (size_t)(row0 + s_r) * II + s_kb;
        uint4 hi, lo;
        cvt_frag(*(const float4*)xr, *(const float4*)(xr + 4), hi, lo);
        aFH[tid] = hi; aFL[tid] = lo;

        const float* hr = h0p + (size_t)(row0 + s_r) * HH + s_kb;
        cvt_frag(*(const float4*)hr, *(const float4*)(hr + 4), hi, lo);
        aFH[512 + tid] = hi; aFL[512 + tid] = lo;
        cvt_frag(*(const float4*)(hr + 256), *(const float4*)(hr + 260), hi, lo);
        aFH[1024 + tid] = hi; aFL[1024 + tid] = lo;
    }
    __syncthreads();

    // ---- x-MFMA for t=0 ----
    f32x4 acc = {0.f, 0.f, 0.f, 0.f};
    #pragma unroll
    for (int q = 0; q < 2; ++q) {
        const int kk = k4 * 2 + q;
        const bf16x8 ah = *(const bf16x8*)&aFH[kk * 64 + lane];
        const bf16x8 al = *(const bf16x8*)&aFL[kk * 64 + lane];
        acc = __builtin_amdgcn_mfma_f32_16x16x32_bf16(ah, wH[q], acc, 0, 0, 0);
        acc = __builtin_amdgcn_mfma_f32_16x16x32_bf16(ah, wL[q], acc, 0, 0, 0);
        acc = __builtin_amdgcn_mfma_f32_16x16x32_bf16(al, wH[q], acc, 0, 0, 0);
    }

    unsigned int* myctr = ctr + rg * 32;

    for (int t = 0; t < TT; ++t) {
        const bool more = (t + 1 < TT);

        // ---- issue x_{t+1} loads early ----
        float4 xv0, xv1;
        if (more) {
            const float* xr = x + ((size_t)(t + 1) * BB + row0 + s_r) * II + s_kb;
            xv0 = *(const float4*)xr;
            xv1 = *(const float4*)(xr + 4);
        }

        // ---- h-MFMA, acc carries x part ----
        #pragma unroll
        for (int q = 0; q < 4; ++q) {
            const int kk = 8 + k4 * 4 + q;
            const bf16x8 ah = *(const bf16x8*)&aFH[kk * 64 + lane];
            const bf16x8 al = *(const bf16x8*)&aFL[kk * 64 + lane];
            acc = __builtin_amdgcn_mfma_f32_16x16x32_bf16(ah, wH[2 + q], acc, 0, 0, 0);
            acc = __builtin_amdgcn_mfma_f32_16x16x32_bf16(ah, wL[2 + q], acc, 0, 0, 0);
            acc = __builtin_amdgcn_mfma_f32_16x16x32_bf16(al, wH[2 + q], acc, 0, 0, 0);
        }

        // ---- publish C partial; stage x_{t+1} ----
        ((f32x4*)red)[wv * 64 + lane] = acc;
        if (more) {
            uint4 hi, lo;
            cvt_frag(xv0, xv1, hi, lo);
            aFH[tid] = hi; aFL[tid] = lo;
        }
        __syncthreads();                        // S1

        if (more && wv >= 2) {
            // ---- consumer waves: x-window MFMA overlaps producers' drain ----
            acc = (f32x4){0.f, 0.f, 0.f, 0.f};
            #pragma unroll
            for (int q = 0; q < 2; ++q) {
                const int kk = k4 * 2 + q;
                const bf16x8 ah = *(const bf16x8*)&aFH[kk * 64 + lane];
                const bf16x8 al = *(const bf16x8*)&aFL[kk * 64 + lane];
                acc = __builtin_amdgcn_mfma_f32_16x16x32_bf16(ah, wH[q], acc, 0, 0, 0);
                acc = __builtin_amdgcn_mfma_f32_16x16x32_bf16(ah, wL[q], acc, 0, 0, 0);
                acc = __builtin_amdgcn_mfma_f32_16x16x32_bf16(al, wH[q], acc, 0, 0, 0);
            }
        }

        // ---- cell update (threads 0..127): out (plain) + hpk (packed) ----
        if (tid < 128) {
            const int r = tid >> 3, m8 = tid & 7;
            const int lane_c_base = 16 * (r >> 2);
            const int reg = r & 3;
            float g4[4];
            #pragma unroll
            for (int g = 0; g < 4; ++g) {
                const int col = g * 8 + m8;
                const int nn  = col >> 4, cl = col & 15;
                const int lc  = cl + lane_c_base;
                float s = b4[g];
                #pragma unroll
                for (int p = 0; p < 4; ++p)
                    s += red[((nn * 4 + p) * 64 + lc) * 4 + reg];
                g4[g] = s;
            }
            const float ig = sigm(g4[0]);
            const float fg = sigm(g4[1]);
            const float gg = fast_tanh(g4[2]);
            const float og = sigm(g4[3]);
            const float cn = fg * c_lds[r][m8] + ig * gg;
            c_lds[r][m8] = cn;
            const float hv = og * fast_tanh(cn);
            out[((size_t)t * BB + row0 + r) * HH + cell0 + m8] = hv;  // plain
            if (more) {
                const unsigned int hb = cvtpk_bf16(hv, hv) & 0xffffu;
                const float hf = __uint_as_float(hb << 16);
                const unsigned int lb = cvtpk_bf16(hv - hf, hv - hf) & 0xffffu;
                coh_store_u(&hpk[((size_t)(t & 1) * BB + row0 + r) * HH
                                 + cell0 + m8], (hb << 16) | lb);
            }
        }

        // ---- drain: only producer waves (0,1) have h stores in flight ----
        if (wv < 2) asm volatile("s_waitcnt vmcnt(0) lgkmcnt(0)" ::: "memory");
        __syncthreads();                        // S2
        if (more) {
            if (tid == 0)
                __hip_atomic_fetch_add(myctr, 1u, __ATOMIC_RELAXED,
                                       __HIP_MEMORY_SCOPE_AGENT);

            if (wv < 2) {
                // ---- producer waves: x-window MFMA during the spin ----
                acc = (f32x4){0.f, 0.f, 0.f, 0.f};
                #pragma unroll
                for (int q = 0; q < 2; ++q) {
                    const int kk = k4 * 2 + q;
                    const bf16x8 ah = *(const bf16x8*)&aFH[kk * 64 + lane];
                    const bf16x8 al = *(const bf16x8*)&aFL[kk * 64 + lane];
                    acc = __builtin_amdgcn_mfma_f32_16x16x32_bf16(ah, wH[q], acc, 0, 0, 0);
                    acc = __builtin_amdgcn_mfma_f32_16x16x32_bf16(ah, wL[q], acc, 0, 0, 0);
                    acc = __builtin_amdgcn_mfma_f32_16x16x32_bf16(al, wH[q], acc, 0, 0, 0);
                }
            }

            // ---- tid0-only spin (single-reader rule) ----
            if (tid == 0) {
                const unsigned int target = 64u * (unsigned int)(t + 1);
                while (__hip_atomic_load(myctr, __ATOMIC_RELAXED,
                                         __HIP_MEMORY_SCOPE_AGENT) < target) {
                    __builtin_amdgcn_s_sleep(1);
                }
            }
            __syncthreads();                    // S3

            // ---- single-shot gather: 16 packed u32 (16B x ... 4 dwordx4) ----
            const unsigned int* hb = hpk + ((size_t)(t & 1) * BB + row0 + s_r) * HH + s_kb;
            uint4 q0, q1, q2, q3;
            asm volatile(
                "global_load_dwordx4 %0, %4, off sc0 sc1\n\t"
                "global_load_dwordx4 %1, %4, off offset:16 sc0 sc1\n\t"
                "global_load_dwordx4 %2, %4, off offset:1024 sc0 sc1\n\t"
                "global_load_dwordx4 %3, %4, off offset:1040 sc0 sc1\n\t"
                "s_waitcnt vmcnt(0)"
                : "=&v"(q0), "=&v"(q1), "=&v"(q2), "=&v"(q3)
                : "v"(hb)
                : "memory");

            // ---- unpack -> fragment hi/lo, stage (linear writes) ----
            {
                uint4 fh, fl;
                unpack8(q0, q1, fh, fl);
                aFH[512 + tid] = fh; aFL[512 + tid] = fl;
                unpack8(q2, q3, fh, fl);
                aFH[1024 + tid] = fh; aFL[1024 + tid] = fl;
            }
            __syncthreads();                    // S4
        }
    }
}

extern "C" void kernel_launch(void* const* d_in, const int* in_sizes, int n_in,
                              void* d_out, int out_size, void* d_ws, size_t ws_size,
                              hipStream_t stream) {
    const float* x  = (const float*)d_in[0];
    const float* Wi = (const float*)d_in[1];
    const float* Wh = (const float*)d_in[2];
    const float* bi = (const float*)d_in[3];
    const float* bh = (const float*)d_in[4];
    const float* h0 = (const float*)d_in[5];
    const float* c0 = (const float*)d_in[6];
    float* out = (float*)d_out;

    unsigned int* hpk = (unsigned int*)d_ws;               // 256 KB
    unsigned int* ctr = (unsigned int*)((char*)d_ws + 2 * BB * HH * 4);

    init_ctr<<<1, 128, 0, stream>>>(ctr);

    void* args[] = { (void*)&x, (void*)&Wi, (void*)&Wh, (void*)&bi,
                     (void*)&bh, (void*)&h0, (void*)&c0, (void*)&out,
                     (void*)&hpk, (void*)&ctr };
    hipError_t e = hipLaunchCooperativeKernel((const void*)lstm_persist,
                                              dim3(NRG * NCG), dim3(THREADS),
                                              args, 0, stream);
    if (e != hipSuccess) {
        (void)hipGetLastError();
        lstm_persist<<<dim3(NRG * NCG), dim3(THREADS), 0, stream>>>(
            x, Wi, Wh, bi, bh, h0, c0, out, hpk, ctr);
    }
}

// Round 19
// 4052.419 us; speedup vs baseline: 2.2799x; 1.0596x over previous
//
#include <hip/hip_runtime.h>
#include <math.h>

// LSTM forward: T=1024, B=64, I=256, H=512 (4H=2048), fp32 in/out.
// Round 19: capacity-minimum rendezvous. Weight capacity (~200KB/block of
//   hi+lo bf16) forces >=32 blocks per row group; R14-R18 ran 64. Here:
//   grid 128 = 4 rg x 32 cg; block = 16 rows x 16 cells (64 gate cols),
//   1024 threads = 16 waves (n4 = gate, k4 = K-chunk) -- per-wave layout
//   IDENTICAL to R14 (48 weight VGPRs, 6 kk slots, 18 MFMA/step).
//   Rendezvous participants 64 -> 32: counter adds/step halved, skew tail
//   max-of-32. Exchange = R18 packed-u32 h (single-shot 2x dwordx4 gather);
//   sync = R14-proven drain (producer waves only) + counter + tid0 spin.
// bf16-split MFMA (R13-verified), W-frags in regs, linear staging (R14).

#define TT      1024
#define BB      64
#define II      256
#define HH      512
#define G4H     2048
#define RPB     16
#define NRG     4
#define NCG     32
#define THREADS 1024

typedef short  bf16x8 __attribute__((ext_vector_type(8)));
typedef float  f32x4  __attribute__((ext_vector_type(4)));

__device__ __forceinline__ unsigned int cvtpk_bf16(float a, float b) {
    unsigned int r;
    asm volatile("v_cvt_pk_bf16_f32 %0, %1, %2" : "=v"(r) : "v"(a), "v"(b));
    return r;   // lo16 = bf16(a), hi16 = bf16(b), RNE
}
__device__ __forceinline__ void coh_store_u(unsigned int* p, unsigned int v) {
    asm volatile("global_store_dword %0, %1, off sc0 sc1"
                 :: "v"(p), "v"(v) : "memory");
}
__device__ __forceinline__ float fast_tanh(float v) {
    const float e = __expf(-2.0f * fabsf(v));
    const float r = (1.0f - e) / (1.0f + e);
    return v < 0.0f ? -r : r;
}
__device__ __forceinline__ float sigm(float v) {
    return 1.0f / (1.0f + __expf(-v));
}

// convert 8 consecutive k-elements of one fragment into hi/lo bf16x8
__device__ __forceinline__ void cvt_frag(float4 v0, float4 v1,
                                         uint4& hi, uint4& lo) {
    hi.x = cvtpk_bf16(v0.x, v0.y);
    hi.y = cvtpk_bf16(v0.z, v0.w);
    hi.z = cvtpk_bf16(v1.x, v1.y);
    hi.w = cvtpk_bf16(v1.z, v1.w);
    lo.x = cvtpk_bf16(v0.x - __uint_as_float(hi.x << 16),
                      v0.y - __uint_as_float(hi.x & 0xffff0000u));
    lo.y = cvtpk_bf16(v0.z - __uint_as_float(hi.y << 16),
                      v0.w - __uint_as_float(hi.y & 0xffff0000u));
    lo.z = cvtpk_bf16(v1.x - __uint_as_float(hi.z << 16),
                      v1.y - __uint_as_float(hi.z & 0xffff0000u));
    lo.w = cvtpk_bf16(v1.z - __uint_as_float(hi.w << 16),
                      v1.w - __uint_as_float(hi.w & 0xffff0000u));
}

// unpack 8 packed u32 (hi16|lo16) -> fragment hi/lo words
// frag word u = (elem 2u in lo16, elem 2u+1 in hi16)
__device__ __forceinline__ void unpack8(uint4 a, uint4 b,
                                        uint4& fh, uint4& fl) {
    fh.x = (a.x >> 16) | (a.y & 0xffff0000u);
    fh.y = (a.z >> 16) | (a.w & 0xffff0000u);
    fh.z = (b.x >> 16) | (b.y & 0xffff0000u);
    fh.w = (b.z >> 16) | (b.w & 0xffff0000u);
    fl.x = (a.x & 0xffffu) | (a.y << 16);
    fl.y = (a.z & 0xffffu) | (a.w << 16);
    fl.z = (b.x & 0xffffu) | (b.y << 16);
    fl.w = (b.z & 0xffffu) | (b.w << 16);
}

__global__ void init_ctr(unsigned int* c) { c[threadIdx.x] = 0; }

__global__ __launch_bounds__(THREADS) void lstm_persist(
    const float* __restrict__ x,    // [T][B][I]
    const float* __restrict__ Wi,   // [I][4H]
    const float* __restrict__ Wh,   // [H][4H]
    const float* __restrict__ bi,   // [4H]
    const float* __restrict__ bh,   // [4H]
    const float* __restrict__ h0p,  // [B][H]
    const float* __restrict__ c0p,  // [B][H]
    float* __restrict__ out,        // [T][B][H]
    unsigned int* __restrict__ hpk, // [2][64][512] packed (hi16|lo16)
    unsigned int* __restrict__ ctr) // [NRG*32], zeroed
{
    const int tid   = threadIdx.x;
    const int cg    = blockIdx.x & 31;
    const int rg    = blockIdx.x >> 5;
    const int row0  = rg * RPB;
    const int cell0 = cg * 16;
    const int wv    = tid >> 6;           // 0..15
    const int lane  = tid & 63;
    const int n4    = wv >> 2;            // gate 0..3 (N-tile)
    const int k4    = wv & 3;             // K-chunk 0..3

    __shared__ uint4 aFH[24 * 64];        // 24,576 B  A hi frags (kk 0..23)
    __shared__ uint4 aFL[24 * 64];        // 24,576 B  A lo
    __shared__ float red[16 * 64 * 4];    // 16,384 B  per-wave C partials
    __shared__ float c_lds[RPB][16];      //  1,024 B  (total 66,560 B)

    // staging geometry
    const int s_ls = tid & 63;
    const int s_r  = s_ls & 15;                  // row within group
    const int s_k2 = ((s_ls >> 4) & 3) * 8;      // k sub-offset
    const int xkk  = tid >> 6;                   // x frag kk (tid<512)
    const int hkc  = (tid >> 6) * 32 + s_k2;     // h-col base 0..511 (all tid)

    // ---- one-time: W fragments -> registers (6 kk slots x hi/lo) ----
    bf16x8 wH[6], wL[6];
    {
        const int J = n4 * HH + cell0 + (lane & 15);   // gate n4, cell col
        #pragma unroll
        for (int s = 0; s < 6; ++s) {
            const int kk = (s < 2) ? (k4 * 2 + s) : (8 + k4 * 4 + (s - 2));
            const int kb = kk * 32 + (lane >> 4) * 8;
            float w[8];
            #pragma unroll
            for (int e = 0; e < 8; ++e) {
                const int k = kb + e;
                w[e] = (k < II) ? Wi[(size_t)k * G4H + J]
                                : Wh[(size_t)(k - II) * G4H + J];
            }
            uint4 hi, lo;
            cvt_frag(make_float4(w[0], w[1], w[2], w[3]),
                     make_float4(w[4], w[5], w[6], w[7]), hi, lo);
            wH[s] = *(bf16x8*)&hi;
            wL[s] = *(bf16x8*)&lo;
        }
    }

    // ---- update-role constants (threads 0..255): r = tid>>4, m = tid&15 ----
    float b4[4];
    if (tid < 256) {
        const int r = tid >> 4, m = tid & 15;
        #pragma unroll
        for (int g = 0; g < 4; ++g)
            b4[g] = bi[g * HH + cell0 + m] + bh[g * HH + cell0 + m];
        c_lds[r][m] = c0p[(size_t)(row0 + r) * HH + cell0 + m];
    }

    // ---- prologue: stage x_0 (tid<512) and h0 (all) fragments ----
    if (tid < 512) {
        const float* xr = x + (size_t)(row0 + s_r) * II + xkk * 32 + s_k2;
        uint4 hi, lo;
        cvt_frag(*(const float4*)xr, *(const float4*)(xr + 4), hi, lo);
        aFH[tid] = hi; aFL[tid] = lo;
    }
    {
        const float* hr = h0p + (size_t)(row0 + s_r) * HH + hkc;
        uint4 hi, lo;
        cvt_frag(*(const float4*)hr, *(const float4*)(hr + 4), hi, lo);
        aFH[512 + tid] = hi; aFL[512 + tid] = lo;
    }
    __syncthreads();

    // ---- x-MFMA for t=0 ----
    f32x4 acc = {0.f, 0.f, 0.f, 0.f};
    #pragma unroll
    for (int q = 0; q < 2; ++q) {
        const int kk = k4 * 2 + q;
        const bf16x8 ah = *(const bf16x8*)&aFH[kk * 64 + lane];
        const bf16x8 al = *(const bf16x8*)&aFL[kk * 64 + lane];
        acc = __builtin_amdgcn_mfma_f32_16x16x32_bf16(ah, wH[q], acc, 0, 0, 0);
        acc = __builtin_amdgcn_mfma_f32_16x16x32_bf16(ah, wL[q], acc, 0, 0, 0);
        acc = __builtin_amdgcn_mfma_f32_16x16x32_bf16(al, wH[q], acc, 0, 0, 0);
    }

    unsigned int* myctr = ctr + rg * 32;

    for (int t = 0; t < TT; ++t) {
        const bool more = (t + 1 < TT);

        // ---- issue x_{t+1} loads early (tid<512) ----
        float4 xv0, xv1;
        if (more && tid < 512) {
            const float* xr = x + ((size_t)(t + 1) * BB + row0 + s_r) * II
                              + xkk * 32 + s_k2;
            xv0 = *(const float4*)xr;
            xv1 = *(const float4*)(xr + 4);
        }

        // ---- h-MFMA, acc carries x part ----
        #pragma unroll
        for (int q = 0; q < 4; ++q) {
            const int kk = 8 + k4 * 4 + q;
            const bf16x8 ah = *(const bf16x8*)&aFH[kk * 64 + lane];
            const bf16x8 al = *(const bf16x8*)&aFL[kk * 64 + lane];
            acc = __builtin_amdgcn_mfma_f32_16x16x32_bf16(ah, wH[2 + q], acc, 0, 0, 0);
            acc = __builtin_amdgcn_mfma_f32_16x16x32_bf16(ah, wL[2 + q], acc, 0, 0, 0);
            acc = __builtin_amdgcn_mfma_f32_16x16x32_bf16(al, wH[2 + q], acc, 0, 0, 0);
        }

        // ---- publish C partial; stage x_{t+1} (tid<512) ----
        ((f32x4*)red)[wv * 64 + lane] = acc;
        if (more && tid < 512) {
            uint4 hi, lo;
            cvt_frag(xv0, xv1, hi, lo);
            aFH[tid] = hi; aFL[tid] = lo;
        }
        __syncthreads();                        // S1

        if (more && wv >= 4) {
            // ---- non-producer waves: x-window overlaps update+drain ----
            acc = (f32x4){0.f, 0.f, 0.f, 0.f};
            #pragma unroll
            for (int q = 0; q < 2; ++q) {
                const int kk = k4 * 2 + q;
                const bf16x8 ah = *(const bf16x8*)&aFH[kk * 64 + lane];
                const bf16x8 al = *(const bf16x8*)&aFL[kk * 64 + lane];
                acc = __builtin_amdgcn_mfma_f32_16x16x32_bf16(ah, wH[q], acc, 0, 0, 0);
                acc = __builtin_amdgcn_mfma_f32_16x16x32_bf16(ah, wL[q], acc, 0, 0, 0);
                acc = __builtin_amdgcn_mfma_f32_16x16x32_bf16(al, wH[q], acc, 0, 0, 0);
            }
        }

        // ---- cell update (threads 0..255): out (plain) + hpk (packed) ----
        if (tid < 256) {
            const int r = tid >> 4, m = tid & 15;
            const int lc  = m + 16 * (r >> 2);   // C lane (m89 layout)
            const int reg = r & 3;
            float g4[4];
            #pragma unroll
            for (int g = 0; g < 4; ++g) {
                float s = b4[g];
                #pragma unroll
                for (int p = 0; p < 4; ++p)
                    s += red[((g * 4 + p) * 64 + lc) * 4 + reg];
                g4[g] = s;
            }
            const float ig = sigm(g4[0]);
            const float fg = sigm(g4[1]);
            const float gg = fast_tanh(g4[2]);
            const float og = sigm(g4[3]);
            const float cn = fg * c_lds[r][m] + ig * gg;
            c_lds[r][m] = cn;
            const float hv = og * fast_tanh(cn);
            out[((size_t)t * BB + row0 + r) * HH + cell0 + m] = hv;   // plain
            if (more) {
                const unsigned int hb = cvtpk_bf16(hv, hv) & 0xffffu;
                const float hf = __uint_as_float(hb << 16);
                const unsigned int lb = cvtpk_bf16(hv - hf, hv - hf) & 0xffffu;
                coh_store_u(&hpk[((size_t)(t & 1) * BB + row0 + r) * HH
                                 + cell0 + m], (hb << 16) | lb);
            }
        }

        // ---- drain: producer waves (0..3) only ----
        if (wv < 4) asm volatile("s_waitcnt vmcnt(0) lgkmcnt(0)" ::: "memory");
        __syncthreads();                        // S2
        if (more) {
            if (tid == 0)
                __hip_atomic_fetch_add(myctr, 1u, __ATOMIC_RELAXED,
                                       __HIP_MEMORY_SCOPE_AGENT);

            if (wv < 4) {
                // ---- producer waves: x-window during the spin ----
                acc = (f32x4){0.f, 0.f, 0.f, 0.f};
                #pragma unroll
                for (int q = 0; q < 2; ++q) {
                    const int kk = k4 * 2 + q;
                    const bf16x8 ah = *(const bf16x8*)&aFH[kk * 64 + lane];
                    const bf16x8 al = *(const bf16x8*)&aFL[kk * 64 + lane];
                    acc = __builtin_amdgcn_mfma_f32_16x16x32_bf16(ah, wH[q], acc, 0, 0, 0);
                    acc = __builtin_amdgcn_mfma_f32_16x16x32_bf16(ah, wL[q], acc, 0, 0, 0);
                    acc = __builtin_amdgcn_mfma_f32_16x16x32_bf16(al, wH[q], acc, 0, 0, 0);
                }
            }

            // ---- tid0-only spin (32 participants) ----
            if (tid == 0) {
                const unsigned int target = 32u * (unsigned int)(t + 1);
                while (__hip_atomic_load(myctr, __ATOMIC_RELAXED,
                                         __HIP_MEMORY_SCOPE_AGENT) < target) {
                    __builtin_amdgcn_s_sleep(1);
                }
            }
            __syncthreads();                    // S3

            // ---- single-shot gather: 8 packed u32 (2x dwordx4) ----
            const unsigned int* hb = hpk + ((size_t)(t & 1) * BB + row0 + s_r) * HH + hkc;
            uint4 q0, q1;
            asm volatile(
                "global_load_dwordx4 %0, %2, off sc0 sc1\n\t"
                "global_load_dwordx4 %1, %2, off offset:16 sc0 sc1\n\t"
                "s_waitcnt vmcnt(0)"
                : "=&v"(q0), "=&v"(q1)
                : "v"(hb)
                : "memory");

            // ---- unpack -> fragment hi/lo, stage (linear writes) ----
            {
                uint4 fh, fl;
                unpack8(q0, q1, fh, fl);
                aFH[512 + tid] = fh; aFL[512 + tid] = fl;
            }
            __syncthreads();                    // S4
        }
    }
}

extern "C" void kernel_launch(void* const* d_in, const int* in_sizes, int n_in,
                              void* d_out, int out_size, void* d_ws, size_t ws_size,
                              hipStream_t stream) {
    const float* x  = (const float*)d_in[0];
    const float* Wi = (const float*)d_in[1];
    const float* Wh = (const float*)d_in[2];
    const float* bi = (const float*)d_in[3];
    const float* bh = (const float*)d_in[4];
    const float* h0 = (const float*)d_in[5];
    const float* c0 = (const float*)d_in[6];
    float* out = (float*)d_out;

    unsigned int* hpk = (unsigned int*)d_ws;               // 256 KB
    unsigned int* ctr = (unsigned int*)((char*)d_ws + 2 * BB * HH * 4);

    init_ctr<<<1, 128, 0, stream>>>(ctr);

    void* args[] = { (void*)&x, (void*)&Wi, (void*)&Wh, (void*)&bi,
                     (void*)&bh, (void*)&h0, (void*)&c0, (void*)&out,
                     (void*)&hpk, (void*)&ctr };
    hipError_t e = hipLaunchCooperativeKernel((const void*)lstm_persist,
                                              dim3(NRG * NCG), dim3(THREADS),
                                              args, 0, stream);
    if (e != hipSuccess) {
        (void)hipGetLastError();
        // 128 blocks, 1 block/CU (LDS+threads) co-reside with plain dispatch
        lstm_persist<<<dim3(NRG * NCG), dim3(THREADS), 0, stream>>>(
            x, Wi, Wh, bi, bh, h0, c0, out, hpk, ctr);
    }
}